// Round 6
// baseline (125.093 us; speedup 1.0000x reference)
//
#include <hip/hip_runtime.h>
#include <math.h>

// MinibatchDiscrimination: B=512, IN=512, OUT=100, K=5
//   M = x @ T.view(512,500);  out[j,o] = sum_i exp(-sum_k|M[i,o,k]-M[j,o,k]|) - 1
//
// R5 lesson: 200-block kernels run at 15% occupancy and stall on load latency.
// Every kernel here has >=356 blocks; gemm/pairwise have 800 (~3 blocks/CU).
//
//  prep : xT[c][i] = x[i][c]; Tst[o][c][8] = {T[c][o][k]*log2(e), 0,0,0}
//         (|s*a - s*b| = s|a-b|, s>0  =>  exp(-n) == exp2(-n_scaled))
//  gemm : grid (8 itile, 100 o), 256 thr. Block = 64 i x 1 o.
//         Thread = 4i x 5k x 32c, consecutive-c lanes (cs = t&3) so xT loads
//         are 4x256B contiguous and Tl LDS reads are conflict-free.
//         Partials ds_add into Mblk[64][9] (stride 9: 2-way banks, not 16).
//         Coalesced f4 writeout to M8o[o][i][8].
//  pair : grid (100 o, 8 jc), 256 thr. Stage M8o[o] (coalesced f4) -> Ms,
//         4 j/thread register-blocked, 16 i-splits of 32 i. VALU-bound.

#define NB    512
#define NIN   512
#define NOUT  100
#define KDIM  5
#define NCOL  500
#define LOG2E 1.44269504088896340736f

// ---------------- prep: transpose x + build padded per-o T columns
__global__ __launch_bounds__(256) void prep_kernel(const float* __restrict__ x,
                                                   const float* __restrict__ T,
                                                   float* __restrict__ xT,
                                                   float* __restrict__ Tst) {
    const int bx = blockIdx.x;
    if (bx < 256) {
        __shared__ float tile[32][33];
        const int tr = bx >> 4, tc = bx & 15;
        const int tx = threadIdx.x & 31, ty = threadIdx.x >> 5;
        #pragma unroll
        for (int l = 0; l < 4; ++l)
            tile[ty + 8 * l][tx] = x[(tr * 32 + ty + 8 * l) * NIN + tc * 32 + tx];
        __syncthreads();
        #pragma unroll
        for (int l = 0; l < 4; ++l)
            xT[(tc * 32 + ty + 8 * l) * NB + tr * 32 + tx] = tile[tx][ty + 8 * l];
    } else {
        const int o = bx - 256;          // 0..99
        const int t = threadIdx.x;
        for (int c = t; c < NB; c += 256) {
            const float* src = T + c * NCOL + o * KDIM;
            float4 a = make_float4(src[0] * LOG2E, src[1] * LOG2E,
                                   src[2] * LOG2E, src[3] * LOG2E);
            float4 b = make_float4(src[4] * LOG2E, 0.f, 0.f, 0.f);
            float* dst = Tst + (o * NB + c) * 8;
            *reinterpret_cast<float4*>(dst)     = a;
            *reinterpret_cast<float4*>(dst + 4) = b;
        }
    }
}

// ---------------- gemm: M8o[o][i][8] = (xT^T @ Tst_o), padded
__global__ __launch_bounds__(256) void gemm_kernel(const float* __restrict__ xT,
                                                   const float* __restrict__ Tst,
                                                   float* __restrict__ M8o) {
    __shared__ float Tl[NB * 8];        // 16 KB
    __shared__ float Mblk[64 * 9];      // stride 9: ds_add banks spread

    const int itile = blockIdx.x;       // 0..7
    const int o     = blockIdx.y;       // 0..99
    const int t     = threadIdx.x;

    // stage T column (coalesced f4, 1024 loads)
    {
        const float4* src = reinterpret_cast<const float4*>(Tst + o * NB * 8);
        float4* dst = reinterpret_cast<float4*>(Tl);
        #pragma unroll
        for (int l = 0; l < 4; ++l) dst[t + l * 256] = src[t + l * 256];
    }
    for (int idx = t; idx < 64 * 9; idx += 256) Mblk[idx] = 0.f;
    __syncthreads();

    const int cs  = t & 3;              // consecutive-c lane interleave
    const int ih  = (t >> 2) & 15;      // 16 groups x 4 i = 64 i
    const int cs2 = t >> 6;             // wave id = c-quarter
    const int i0  = itile * 64 + ih * 4;

    float acc[4][5];
    #pragma unroll
    for (int r = 0; r < 4; ++r)
        #pragma unroll
        for (int k = 0; k < 5; ++k) acc[r][k] = 0.f;

    int c = cs2 * 128 + cs;
    #pragma unroll 8
    for (int it = 0; it < 32; ++it, c += 4) {
        const float4 xv  = *reinterpret_cast<const float4*>(&xT[c * NB + i0]);
        const float4 t03 = *reinterpret_cast<const float4*>(&Tl[c * 8]);
        const float  t4  = Tl[c * 8 + 4];
        const float xr[4] = {xv.x, xv.y, xv.z, xv.w};
        const float tk[5] = {t03.x, t03.y, t03.z, t03.w, t4};
        #pragma unroll
        for (int r = 0; r < 4; ++r)
            #pragma unroll
            for (int k = 0; k < 5; ++k)
                acc[r][k] = fmaf(xr[r], tk[k], acc[r][k]);
    }

    #pragma unroll
    for (int r = 0; r < 4; ++r)
        #pragma unroll
        for (int k = 0; k < 5; ++k)
            atomicAdd(&Mblk[(ih * 4 + r) * 9 + k], acc[r][k]);   // ds_add_f32
    __syncthreads();

    if (t < 64) {
        float4 a = make_float4(Mblk[t * 9 + 0], Mblk[t * 9 + 1],
                               Mblk[t * 9 + 2], Mblk[t * 9 + 3]);
        float4 b = make_float4(Mblk[t * 9 + 4], 0.f, 0.f, 0.f);
        float* dst = M8o + (o * NB + itile * 64 + t) * 8;
        *reinterpret_cast<float4*>(dst)     = a;
        *reinterpret_cast<float4*>(dst + 4) = b;
    }
}

// ---------------- pairwise: out[j][o] = sum_i exp2(-sum_k|.|) - 1
__global__ __launch_bounds__(256) void pairwise_kernel(const float* __restrict__ M8o,
                                                       float* __restrict__ out) {
    __shared__ float Ms[NB * 8];        // 16 KB
    __shared__ float Pw[16][16][4];     // [is][jg][jj]

    const int o  = blockIdx.x;          // 0..99
    const int jc = blockIdx.y;          // 0..7
    const int t  = threadIdx.x;

    // stage (coalesced f4)
    {
        const float4* src = reinterpret_cast<const float4*>(M8o + o * NB * 8);
        float4* dst = reinterpret_cast<float4*>(Ms);
        #pragma unroll
        for (int l = 0; l < 4; ++l) dst[t + l * 256] = src[t + l * 256];
    }
    __syncthreads();

    const int is = t & 15;              // 16 i-splits (i = it*16 + is)
    const int jg = t >> 4;              // 16 j-groups x 4 j
    const int jbase = jc * 64 + jg * 4;

    float jv[4][5];
    #pragma unroll
    for (int jj = 0; jj < 4; ++jj) {
        const float* m = &Ms[(jbase + jj) * 8];
        #pragma unroll
        for (int k = 0; k < 5; ++k) jv[jj][k] = m[k];
    }

    float acc[4] = {0.f, 0.f, 0.f, 0.f};
    #pragma unroll 4
    for (int it = 0; it < 32; ++it) {
        const float* m = &Ms[(it * 16 + is) * 8];
        const float m0 = m[0], m1 = m[1], m2 = m[2], m3 = m[3], m4 = m[4];
        #pragma unroll
        for (int jj = 0; jj < 4; ++jj) {
            const float n = fabsf(m0 - jv[jj][0]) + fabsf(m1 - jv[jj][1])
                          + fabsf(m2 - jv[jj][2]) + fabsf(m3 - jv[jj][3])
                          + fabsf(m4 - jv[jj][4]);
            acc[jj] += exp2f(-n);       // pre-scaled by log2e -> e^{-norm}
        }
    }

    *reinterpret_cast<float4*>(&Pw[is][jg][0]) =
        make_float4(acc[0], acc[1], acc[2], acc[3]);
    __syncthreads();

    if (t < 64) {
        const int g = t >> 2, jj = t & 3;
        float tot = -1.0f;              // remove exp(0) self-term
        #pragma unroll
        for (int s = 0; s < 16; ++s) tot += Pw[s][g][jj];
        out[(jc * 64 + g * 4 + jj) * NOUT + o] = tot;
    }
}

extern "C" void kernel_launch(void* const* d_in, const int* in_sizes, int n_in,
                              void* d_out, int out_size, void* d_ws, size_t ws_size,
                              hipStream_t stream) {
    const float* x = (const float*)d_in[0];   // [512,512]
    const float* T = (const float*)d_in[1];   // [512,500]
    float* xT  = (float*)d_ws;                // 512*512          = 262144 f
    float* Tst = xT + NB * NIN;               // 100*512*8        = 409600 f
    float* M8o = Tst + NOUT * NB * 8;         // 100*512*8        = 409600 f
    float* out = (float*)d_out;               // [512,100]

    prep_kernel<<<356, 256, 0, stream>>>(x, T, xT, Tst);
    gemm_kernel<<<dim3(8, NOUT), 256, 0, stream>>>(xT, Tst, M8o);
    pairwise_kernel<<<dim3(NOUT, 8), 256, 0, stream>>>(M8o, out);
}

// Round 8
// 85.446 us; speedup vs baseline: 1.4640x; 1.4640x over previous
//
#include <hip/hip_runtime.h>
#include <math.h>

// MinibatchDiscrimination: B=512, IN=512, OUT=100, K=5
//   M = x @ T.view(512,500);  out[j,o] = sum_i exp(-sum_k|M[i,o,k]-M[j,o,k]|) - 1
//
// R7 post-mortem: cooperative launch silently failed (never ran). Back to
// regular launches; minimize dispatches (each costs ~6-9us of gap) and keep
// every kernel >=800 blocks with small LDS (R1/R5/R6: low-occupancy kernels
// stall on load latency).
//
// 2 dispatches:
//  gemm : grid (8 itile, 100 o) = 800 blocks, 256 thr, ~26KB LDS (4+ blk/CU).
//         Full K=512 in 8 staged rounds. A-tile in LDS (b128 reads, stride
//         72 keeps f4 16B-aligned); T[c][o*5+k] via wave-uniform s_load
//         (readfirstlane(waveid) -> scalar address; zero VGPR/LDS cost for B
//         -- the fix for R6's 24-VGPR load serialization). 4 c-quarter
//         partials reduced once via LDS; x LOG2E at writeout into
//         M8o[o][i][8]  (|s*a-s*b| = s|a-b|, s>0 => exp(-n) == exp2(-n')).
//  pair : R6's proven pairwise, grid (100 o, 8 jc), 4 j/thread.

#define NB    512
#define NIN   512
#define NOUT  100
#define KDIM  5
#define NCOL  500
#define LOG2E 1.44269504088896340736f

// ---------------- gemm: M8o[o][i][8] = log2e * (x @ T[:,o,:])
__global__ __launch_bounds__(256) void gemm_kernel(const float* __restrict__ A,
                                                   const float* __restrict__ Tg,
                                                   float* __restrict__ M8o) {
    __shared__ float As[64][72];      // 18.4 KB; stride 72: f4 rows 16B-aligned
    __shared__ float Pr[4][64][8];    // 8 KB partials

    const int itile = blockIdx.x;     // 0..7
    const int o     = blockIdx.y;     // 0..99
    const int t     = threadIdx.x;
    const int lane  = t & 63;         // i within tile
    const int cq    = __builtin_amdgcn_readfirstlane(t >> 6);  // wave id 0..3

    const float* To = Tg + o * KDIM;  // column base (uniform)

    float acc[5] = {0.f, 0.f, 0.f, 0.f, 0.f};

    for (int ct = 0; ct < 8; ++ct) {
        __syncthreads();
        // stage A tile: rows itile*64.., cols ct*64.. (1024 f4, coalesced)
        #pragma unroll
        for (int l = 0; l < 4; ++l) {
            const int idx = t + l * 256;
            const int row = idx >> 4, q = idx & 15;
            *reinterpret_cast<float4*>(&As[row][q * 4]) =
                *reinterpret_cast<const float4*>(
                    &A[(itile * 64 + row) * NIN + ct * 64 + q * 4]);
        }
        __syncthreads();

        const int cb = ct * 64 + cq * 16;      // scalar (uniform) c-base
        #pragma unroll
        for (int cc = 0; cc < 16; cc += 4) {
            const float4 xv = *reinterpret_cast<const float4*>(&As[lane][cq * 16 + cc]);
            const float xr[4] = {xv.x, xv.y, xv.z, xv.w};
            #pragma unroll
            for (int q = 0; q < 4; ++q) {
                const float* tp = To + (cb + cc + q) * NCOL;   // uniform -> s_load
                #pragma unroll
                for (int k = 0; k < 5; ++k)
                    acc[k] = fmaf(xr[q], tp[k], acc[k]);
            }
        }
    }

    // reduce the 4 c-quarters
    #pragma unroll
    for (int k = 0; k < 5; ++k) Pr[cq][lane][k] = acc[k];
    __syncthreads();

    if (t < 64) {
        float s[5];
        #pragma unroll
        for (int k = 0; k < 5; ++k)
            s[k] = (Pr[0][t][k] + Pr[1][t][k] + Pr[2][t][k] + Pr[3][t][k]) * LOG2E;
        float* dst = M8o + (o * NB + itile * 64 + t) * 8;
        *reinterpret_cast<float4*>(dst)     = make_float4(s[0], s[1], s[2], s[3]);
        *reinterpret_cast<float4*>(dst + 4) = make_float4(s[4], 0.f, 0.f, 0.f);
    }
}

// ---------------- pairwise: out[j][o] = sum_i exp2(-sum_k|.|) - 1  (R6-proven)
__global__ __launch_bounds__(256) void pairwise_kernel(const float* __restrict__ M8o,
                                                       float* __restrict__ out) {
    __shared__ float Ms[NB * 8];        // 16 KB
    __shared__ float Pw[16][16][4];     // [is][jg][jj]

    const int o  = blockIdx.x;          // 0..99
    const int jc = blockIdx.y;          // 0..7
    const int t  = threadIdx.x;

    // stage (coalesced f4)
    {
        const float4* src = reinterpret_cast<const float4*>(M8o + o * NB * 8);
        float4* dst = reinterpret_cast<float4*>(Ms);
        #pragma unroll
        for (int l = 0; l < 4; ++l) dst[t + l * 256] = src[t + l * 256];
    }
    __syncthreads();

    const int is = t & 15;              // 16 i-splits (i = it*16 + is)
    const int jg = t >> 4;              // 16 j-groups x 4 j
    const int jbase = jc * 64 + jg * 4;

    float jv[4][5];
    #pragma unroll
    for (int jj = 0; jj < 4; ++jj) {
        const float* m = &Ms[(jbase + jj) * 8];
        #pragma unroll
        for (int k = 0; k < 5; ++k) jv[jj][k] = m[k];
    }

    float acc[4] = {0.f, 0.f, 0.f, 0.f};
    #pragma unroll 4
    for (int it = 0; it < 32; ++it) {
        const float* m = &Ms[(it * 16 + is) * 8];
        const float m0 = m[0], m1 = m[1], m2 = m[2], m3 = m[3], m4 = m[4];
        #pragma unroll
        for (int jj = 0; jj < 4; ++jj) {
            const float n = fabsf(m0 - jv[jj][0]) + fabsf(m1 - jv[jj][1])
                          + fabsf(m2 - jv[jj][2]) + fabsf(m3 - jv[jj][3])
                          + fabsf(m4 - jv[jj][4]);
            acc[jj] += exp2f(-n);       // pre-scaled by log2e -> e^{-norm}
        }
    }

    *reinterpret_cast<float4*>(&Pw[is][jg][0]) =
        make_float4(acc[0], acc[1], acc[2], acc[3]);
    __syncthreads();

    if (t < 64) {
        const int g = t >> 2, jj = t & 3;
        float tot = -1.0f;              // remove exp(0) self-term
        #pragma unroll
        for (int s = 0; s < 16; ++s) tot += Pw[s][g][jj];
        out[(jc * 64 + g * 4 + jj) * NOUT + o] = tot;
    }
}

extern "C" void kernel_launch(void* const* d_in, const int* in_sizes, int n_in,
                              void* d_out, int out_size, void* d_ws, size_t ws_size,
                              hipStream_t stream) {
    const float* x = (const float*)d_in[0];   // [512,512]
    const float* T = (const float*)d_in[1];   // [512,500]
    float* M8o = (float*)d_ws;                // 100*512*8 f = 1.6 MB
    float* out = (float*)d_out;               // [512,100]

    gemm_kernel<<<dim3(8, NOUT), 256, 0, stream>>>(x, T, M8o);
    pairwise_kernel<<<dim3(NOUT, 8), 256, 0, stream>>>(M8o, out);
}